// Round 20
// baseline (47.032 us; speedup 1.0000x reference)
//
#include <hip/hip_runtime.h>
#include <hip/hip_fp16.h>
#include <math.h>

#define NQ 8
#define DK 64
#define NB 8
#define NS 1024
#define RB 8            // rows per block in attn kernel
#define EPITCH 1032     // padded halfs per e16 row

typedef _Float16 h2v __attribute__((ext_vector_type(2)));

__device__ __forceinline__ float fdot2h(unsigned qu, unsigned ku, float acc) {
#if defined(__has_builtin) && __has_builtin(__builtin_amdgcn_fdot2)
    union { unsigned u; h2v h; } a, b;
    a.u = qu; b.u = ku;
    return __builtin_amdgcn_fdot2(a.h, b.h, acc, false);
#else
    __half2 qh = *(__half2*)&qu, kh = *(__half2*)&ku;
    float2 qf = __half22float2(qh), kf = __half22float2(kh);
    return fmaf(qf.x, kf.x, fmaf(qf.y, kf.y, acc));
#endif
}

// density feature from angles: d0,d1,ur,ui (fp32)
__device__ __forceinline__ void qk_density(float s, float c,
                                           const float* t6,
                                           float& d0, float& d1, float& ur, float& ui) {
    float ct = t6[0], st = t6[1], cmpo = t6[2], smpo = t6[3], cpmo = t6[4], spmo = t6[5];
    float a = ct * c, b2 = st * s, cc = st * c, d2 = ct * s;
    float a0re =  cmpo * a - cpmo * b2;
    float a0im = -smpo * a - spmo * b2;
    float a1re =  cpmo * cc + cmpo * d2;
    float a1im = -spmo * cc + smpo * d2;
    d0 = fmaf(a0re, a0re, a0im * a0im);
    d1 = fmaf(a1re, a1re, a1im * a1im);
    ur = fmaf(a1re, a0re, a1im * a0im);
    ui = fmaf(a1im, a0re, -a1re * a0im);
}

__device__ __forceinline__ void theta_table(const float* __restrict__ thp, int n, float* t6) {
    float phi = thp[n * 3 + 0], th = thp[n * 3 + 1], om = thp[n * 3 + 2];
    float st, ct; __sincosf(0.5f * th, &st, &ct);
    float smpo, cmpo; __sincosf(0.5f * (phi + om), &smpo, &cmpo);
    float spmo, cpmo; __sincosf(0.5f * (phi - om), &spmo, &cpmo);
    t6[0] = ct; t6[1] = st; t6[2] = cmpo; t6[3] = smpo; t6[4] = cpmo; t6[5] = spmo;
}

__device__ __forceinline__ void tanh_sincos(float xin, float& s, float& c) {
    float ex = __expf(2.0f * xin);               // fast tanh
    float xn = 1.0f - 2.0f / (ex + 1.0f);
    __sincosf(xn * 1.57079632679489662f, &s, &c);
}

// ---------------- prep: v2 fp16 GEMM (blocks 0..1023) + K density features ----------------
// kdh fp16 [tok][n*4 + {d0,d1,2ur,2ui}]; v2 fp16 pair-interleaved [b][pair][d][t&1].
__global__ __launch_bounds__(256) void prep_kernel(
    const float* __restrict__ x,
    const float* __restrict__ theta_k,
    const float* __restrict__ Wv,
    const float* __restrict__ bv,
    __half* __restrict__ kdh,
    __half* __restrict__ v2) {
    int bid = blockIdx.x;
    int tid = threadIdx.x;
    if (bid < 1024) {
        // values for a token PAIR at fixed d -> one coalesced half2 store
        int gp = bid * 4 + (tid >> 6);        // global pair 0..4095
        int d = tid & 63;
        int t0 = gp * 2;
        const float4* x0 = (const float4*)(x + (size_t)t0 * DK);
        const float4* x1 = (const float4*)(x + (size_t)(t0 + 1) * DK);
        const float4* wr = (const float4*)(Wv + (size_t)d * DK);
        float p0 = bv[d], p1 = bv[d], q0 = 0.f, q1 = 0.f;
#pragma unroll
        for (int j = 0; j < DK / 4; ++j) {
            float4 wv = wr[j];
            float4 a = x0[j], b = x1[j];
            p0 = fmaf(a.x, wv.x, p0); q0 = fmaf(a.y, wv.y, q0);
            p0 = fmaf(a.z, wv.z, p0); q0 = fmaf(a.w, wv.w, q0);
            p1 = fmaf(b.x, wv.x, p1); q1 = fmaf(b.y, wv.y, q1);
            p1 = fmaf(b.z, wv.z, p1); q1 = fmaf(b.w, wv.w, q1);
        }
        int b = t0 >> 10, pi = (t0 & 1023) >> 1;
        __half2 hv = __floats2half2_rn(p0 + q0, p1 + q1);
        *(__half2*)&v2[((size_t)(b * 512 + pi) * 64 + d) * 2] = hv;
    } else {
        // K density features
        __shared__ float tk[NQ][6];
        if (tid < NQ) theta_table(theta_k, tid, tk[tid]);
        __syncthreads();

        int gid = (bid - 1024) * 256 + tid;   // 0..65535
        int tok = gid >> 3;
        int n = gid & 7;
        float s, c;
        tanh_sincos(x[(size_t)tok * DK + n], s, c);
        float d0, d1, ur, ui;
        qk_density(s, c, tk[n], d0, d1, ur, ui);
        __half2* kp = (__half2*)(kdh + (size_t)tok * 32 + n * 4);
        kp[0] = __floats2half2_rn(d0, d1);
        kp[1] = __floats2half2_rn(2.f * ur, 2.f * ui);
    }
}

// ---------------- attn: 512 threads (8 waves), block owns 8 rows ----------------
// Phase 1: wave w owns tokens [128w,128(w+1)) in kv[2][4]; q wave-redundant via readlane.
__global__ __launch_bounds__(512, 4) void attn_kernel(
    const float* __restrict__ x,
    const float* __restrict__ theta_q,
    const __half* __restrict__ kdh,
    const __half* __restrict__ v2,
    float* __restrict__ out, float* __restrict__ attn) {
    __shared__ __align__(16) unsigned char smem[RB * EPITCH * 2];   // 16.5 KB
    __half (*e16)[EPITCH] = (__half(*)[EPITCH])smem;
    float* red = (float*)smem;          // aliased [32][2][64] fp32 after PV
    __shared__ float red_lds[8][RB];
    __shared__ float inv_lds[RB];

    int tid = threadIdx.x;
    int gr0 = blockIdx.x * RB;            // global row base (= b*NS + s0)
    int b = gr0 >> 10;
    int w = tid >> 6, lane = tid & 63;

    // ---- Phase A: wave-redundant q features; lane l holds row l>>3, qubit l&7 ----
    unsigned vq0, vq1;
    {
        int r0 = lane >> 3, n0 = lane & 7;
        float t6[6];
        theta_table(theta_q, n0, t6);
        float s, c;
        tanh_sincos(x[(size_t)(gr0 + r0) * DK + n0], s, c);
        float d0, d1, ur, ui;
        qk_density(s, c, t6, d0, d1, ur, ui);
        __half2 h0 = __floats2half2_rn(d0, d1);
        __half2 h1 = __floats2half2_rn(ur, ui);
        vq0 = *(unsigned*)&h0;
        vq1 = *(unsigned*)&h1;
    }

    // ---- Phase 1: load wave's K slice (2 tokens per lane, 32 VGPRs) ----
    const __half* kfb = kdh + (size_t)b * NS * 32;
    int t0 = w * 128;
    uint4 kv[2][4];
#pragma unroll
    for (int j = 0; j < 2; ++j) {
        const uint4* kp = (const uint4*)(kfb + (size_t)(t0 + j * 64 + lane) * 32);
        kv[j][0] = kp[0]; kv[j][1] = kp[1]; kv[j][2] = kp[2]; kv[j][3] = kp[3];
    }

    float sums[RB];
#pragma unroll
    for (int r = 0; r < RB; ++r) sums[r] = 0.f;

#pragma unroll
    for (int r = 0; r < RB; ++r) {
        unsigned sq[16];
#pragma unroll
        for (int n = 0; n < 8; ++n) {
            sq[2 * n + 0] = __builtin_amdgcn_readlane(vq0, r * 8 + n);
            sq[2 * n + 1] = __builtin_amdgcn_readlane(vq1, r * 8 + n);
        }
#pragma unroll
        for (int j = 0; j < 2; ++j) {
            float m0 = fdot2h(sq[ 0], kv[j][0].x, fdot2h(sq[ 1], kv[j][0].y, 0.f));
            float m1 = fdot2h(sq[ 2], kv[j][0].z, fdot2h(sq[ 3], kv[j][0].w, 0.f));
            float m2 = fdot2h(sq[ 4], kv[j][1].x, fdot2h(sq[ 5], kv[j][1].y, 0.f));
            float m3 = fdot2h(sq[ 6], kv[j][1].z, fdot2h(sq[ 7], kv[j][1].w, 0.f));
            float m4 = fdot2h(sq[ 8], kv[j][2].x, fdot2h(sq[ 9], kv[j][2].y, 0.f));
            float m5 = fdot2h(sq[10], kv[j][2].z, fdot2h(sq[11], kv[j][2].w, 0.f));
            float m6 = fdot2h(sq[12], kv[j][3].x, fdot2h(sq[13], kv[j][3].y, 0.f));
            float m7 = fdot2h(sq[14], kv[j][3].z, fdot2h(sq[15], kv[j][3].w, 0.f));
            float core = ((m0 * m1) * (m2 * m3)) * ((m4 * m5) * (m6 * m7));
            float e = __expf(fmaf(core, 0.5f, 0.5f));   // score in [0.5,1] -> no max
            e16[r][t0 + j * 64 + lane] = __float2half_rn(e);
            sums[r] += e;
        }
    }

    // per-wave partial row sums -> cross-wave combine (8 waves)
#pragma unroll
    for (int r = 0; r < RB; ++r) {
#pragma unroll
        for (int m = 1; m < 64; m <<= 1) sums[r] += __shfl_xor(sums[r], m, 64);
    }
    if (lane == 0) {
#pragma unroll
        for (int r = 0; r < RB; ++r) red_lds[w][r] = sums[r];
    }
    __syncthreads();
    if (tid < RB) {
        float s = 0.f;
#pragma unroll
        for (int g = 0; g < 8; ++g) s += red_lds[g][tid];
        inv_lds[tid] = 1.f / s;
    }
    __syncthreads();

    // ---- Phase 2: write normalized attn (coalesced float2, 512 threads) ----
    float* ab = attn + (size_t)gr0 * NS;
#pragma unroll
    for (int r = 0; r < RB; ++r) {
        float iv = inv_lds[r];
        unsigned raw = *(const unsigned*)&e16[r][tid * 2];
        float2 f = __half22float2(*(__half2*)&raw);
        *(float2*)&ab[(size_t)r * NS + tid * 2] = make_float2(f.x * iv, f.y * iv);
    }

    // ---- Phase 3: PV via dot2, consecutive-pair chunks (b128 e-reads) ----
    // thread (tg 0..31, dg 0..15): pairs p = jj*128 + tg*4 + i, jj<4
    int tg = tid >> 4, dg = tid & 15;
    const __half* v2l = v2 + (size_t)b * 512 * 128 + dg * 8;
    float acc[RB][4];
#pragma unroll
    for (int r = 0; r < RB; ++r) { acc[r][0] = acc[r][1] = acc[r][2] = acc[r][3] = 0.f; }

    for (int jj = 0; jj < 4; ++jj) {
        int p0 = jj * 128 + tg * 4;
        uint4 vv0 = *(const uint4*)(v2l + (size_t)(p0 + 0) * 128);
        uint4 vv1 = *(const uint4*)(v2l + (size_t)(p0 + 1) * 128);
        uint4 vv2 = *(const uint4*)(v2l + (size_t)(p0 + 2) * 128);
        uint4 vv3 = *(const uint4*)(v2l + (size_t)(p0 + 3) * 128);
#pragma unroll
        for (int r = 0; r < RB; ++r) {
            uint4 ep = *(const uint4*)&e16[r][2 * p0];   // 4 pairs of e (16B)
            acc[r][0] = fdot2h(ep.x, vv0.x, acc[r][0]);
            acc[r][1] = fdot2h(ep.x, vv0.y, acc[r][1]);
            acc[r][2] = fdot2h(ep.x, vv0.z, acc[r][2]);
            acc[r][3] = fdot2h(ep.x, vv0.w, acc[r][3]);
            acc[r][0] = fdot2h(ep.y, vv1.x, acc[r][0]);
            acc[r][1] = fdot2h(ep.y, vv1.y, acc[r][1]);
            acc[r][2] = fdot2h(ep.y, vv1.z, acc[r][2]);
            acc[r][3] = fdot2h(ep.y, vv1.w, acc[r][3]);
            acc[r][0] = fdot2h(ep.z, vv2.x, acc[r][0]);
            acc[r][1] = fdot2h(ep.z, vv2.y, acc[r][1]);
            acc[r][2] = fdot2h(ep.z, vv2.z, acc[r][2]);
            acc[r][3] = fdot2h(ep.z, vv2.w, acc[r][3]);
            acc[r][0] = fdot2h(ep.w, vv3.x, acc[r][0]);
            acc[r][1] = fdot2h(ep.w, vv3.y, acc[r][1]);
            acc[r][2] = fdot2h(ep.w, vv3.z, acc[r][2]);
            acc[r][3] = fdot2h(ep.w, vv3.w, acc[r][3]);
        }
    }

    // ---- out reduce: alias e16 as [32 tg][2 r][64 d] fp32 scratch, 4 rounds ----
#pragma unroll
    for (int h = 0; h < 4; ++h) {
        __syncthreads();    // previous readers of e16/red done
#pragma unroll
        for (int r = 0; r < 2; ++r) {
            *(float4*)&red[((size_t)tg * 2 + r) * 64 + dg * 4] =
                make_float4(acc[h * 2 + r][0], acc[h * 2 + r][1],
                            acc[h * 2 + r][2], acc[h * 2 + r][3]);
        }
        __syncthreads();
        if (tid < 128) {
            int r2 = tid >> 6, d = tid & 63;
            float o = 0.f;
#pragma unroll
            for (int g = 0; g < 32; ++g) o += red[((size_t)g * 2 + r2) * 64 + d];
            out[((size_t)(gr0 + h * 2 + r2)) * DK + d] = o * inv_lds[h * 2 + r2];
        }
    }
}

extern "C" void kernel_launch(void* const* d_in, const int* in_sizes, int n_in,
                              void* d_out, int out_size, void* d_ws, size_t ws_size,
                              hipStream_t stream) {
    const float* x       = (const float*)d_in[0];
    const float* theta_q = (const float*)d_in[1];
    const float* theta_k = (const float*)d_in[2];
    const float* W_v     = (const float*)d_in[3];
    const float* b_v     = (const float*)d_in[4];

    float* out  = (float*)d_out;                        // [8,1024,64]
    float* attn = (float*)d_out + (size_t)NB * NS * DK; // [8,1024,1024]

    __half* kdh = (__half*)d_ws;                         // 512 KB fp16
    __half* v2  = kdh + (size_t)NB * NS * 32;            // 1 MB fp16 (pair-interleaved V)

    prep_kernel<<<1024 + NB * NS * NQ / 256, 256, 0, stream>>>(
        x, theta_k, W_v, b_v, kdh, v2);
    attn_kernel<<<NB * NS / RB, 512, 0, stream>>>(x, theta_q, kdh, v2, out, attn);
}

// Round 21
// 44.499 us; speedup vs baseline: 1.0569x; 1.0569x over previous
//
#include <hip/hip_runtime.h>
#include <hip/hip_fp16.h>
#include <math.h>

#define NQ 8
#define DK 64
#define NB 8
#define NS 1024
#define RB 8            // rows per block in attn kernel
#define EPITCH 1032     // padded halfs per e16 row

typedef _Float16 h2v __attribute__((ext_vector_type(2)));

__device__ __forceinline__ float fdot2h(unsigned qu, unsigned ku, float acc) {
#if defined(__has_builtin) && __has_builtin(__builtin_amdgcn_fdot2)
    union { unsigned u; h2v h; } a, b;
    a.u = qu; b.u = ku;
    return __builtin_amdgcn_fdot2(a.h, b.h, acc, false);
#else
    __half2 qh = *(__half2*)&qu, kh = *(__half2*)&ku;
    float2 qf = __half22float2(qh), kf = __half22float2(kh);
    return fmaf(qf.x, kf.x, fmaf(qf.y, kf.y, acc));
#endif
}

// density feature from angles: d0,d1,ur,ui (fp32)
__device__ __forceinline__ void qk_density(float s, float c,
                                           const float* t6,
                                           float& d0, float& d1, float& ur, float& ui) {
    float ct = t6[0], st = t6[1], cmpo = t6[2], smpo = t6[3], cpmo = t6[4], spmo = t6[5];
    float a = ct * c, b2 = st * s, cc = st * c, d2 = ct * s;
    float a0re =  cmpo * a - cpmo * b2;
    float a0im = -smpo * a - spmo * b2;
    float a1re =  cpmo * cc + cmpo * d2;
    float a1im = -spmo * cc + smpo * d2;
    d0 = fmaf(a0re, a0re, a0im * a0im);
    d1 = fmaf(a1re, a1re, a1im * a1im);
    ur = fmaf(a1re, a0re, a1im * a0im);
    ui = fmaf(a1im, a0re, -a1re * a0im);
}

__device__ __forceinline__ void theta_table(const float* __restrict__ thp, int n, float* t6) {
    float phi = thp[n * 3 + 0], th = thp[n * 3 + 1], om = thp[n * 3 + 2];
    float st, ct; __sincosf(0.5f * th, &st, &ct);
    float smpo, cmpo; __sincosf(0.5f * (phi + om), &smpo, &cmpo);
    float spmo, cpmo; __sincosf(0.5f * (phi - om), &spmo, &cpmo);
    t6[0] = ct; t6[1] = st; t6[2] = cmpo; t6[3] = smpo; t6[4] = cpmo; t6[5] = spmo;
}

__device__ __forceinline__ void tanh_sincos(float xin, float& s, float& c) {
    float ex = __expf(2.0f * xin);               // fast tanh
    float xn = 1.0f - 2.0f / (ex + 1.0f);
    __sincosf(xn * 1.57079632679489662f, &s, &c);
}

// ---------------- prep: v2 fp16 GEMM (blocks 0..1023) + K density features ----------------
// kdh fp16 [tok][n*4 + {d0,d1,2ur,2ui}]; v2 fp16 pair-interleaved [b][pair][d][t&1].
__global__ __launch_bounds__(256) void prep_kernel(
    const float* __restrict__ x,
    const float* __restrict__ theta_k,
    const float* __restrict__ Wv,
    const float* __restrict__ bv,
    __half* __restrict__ kdh,
    __half* __restrict__ v2) {
    int bid = blockIdx.x;
    int tid = threadIdx.x;
    if (bid < 1024) {
        // values for a token PAIR at fixed d -> one coalesced half2 store
        int gp = bid * 4 + (tid >> 6);        // global pair 0..4095
        int d = tid & 63;
        int t0 = gp * 2;
        const float4* x0 = (const float4*)(x + (size_t)t0 * DK);
        const float4* x1 = (const float4*)(x + (size_t)(t0 + 1) * DK);
        const float4* wr = (const float4*)(Wv + (size_t)d * DK);
        float p0 = bv[d], p1 = bv[d], q0 = 0.f, q1 = 0.f;
#pragma unroll
        for (int j = 0; j < DK / 4; ++j) {
            float4 wv = wr[j];
            float4 a = x0[j], b = x1[j];
            p0 = fmaf(a.x, wv.x, p0); q0 = fmaf(a.y, wv.y, q0);
            p0 = fmaf(a.z, wv.z, p0); q0 = fmaf(a.w, wv.w, q0);
            p1 = fmaf(b.x, wv.x, p1); q1 = fmaf(b.y, wv.y, q1);
            p1 = fmaf(b.z, wv.z, p1); q1 = fmaf(b.w, wv.w, q1);
        }
        int b = t0 >> 10, pi = (t0 & 1023) >> 1;
        __half2 hv = __floats2half2_rn(p0 + q0, p1 + q1);
        *(__half2*)&v2[((size_t)(b * 512 + pi) * 64 + d) * 2] = hv;
    } else {
        // K density features
        __shared__ float tk[NQ][6];
        if (tid < NQ) theta_table(theta_k, tid, tk[tid]);
        __syncthreads();

        int gid = (bid - 1024) * 256 + tid;   // 0..65535
        int tok = gid >> 3;
        int n = gid & 7;
        float s, c;
        tanh_sincos(x[(size_t)tok * DK + n], s, c);
        float d0, d1, ur, ui;
        qk_density(s, c, tk[n], d0, d1, ur, ui);
        __half2* kp = (__half2*)(kdh + (size_t)tok * 32 + n * 4);
        kp[0] = __floats2half2_rn(d0, d1);
        kp[1] = __floats2half2_rn(2.f * ur, 2.f * ui);
    }
}

// ---------------- attn: wave-redundant q-in-VGPR -> scores -> softmax -> attn + dot2 PV ----------------
// 1024 blocks x 256 threads (4 waves); block owns 8 rows of one batch.
__global__ __launch_bounds__(256, 4) void attn_kernel(
    const float* __restrict__ x,
    const float* __restrict__ theta_q,
    const __half* __restrict__ kdh,
    const __half* __restrict__ v2,
    float* __restrict__ out, float* __restrict__ attn) {
    __shared__ __align__(16) unsigned char smem[RB * EPITCH * 2];   // 16.5 KB
    __half (*e16)[EPITCH] = (__half(*)[EPITCH])smem;
    float* red = (float*)smem;          // aliased [16][4][64] fp32 after PV
    __shared__ float red_lds[4][RB];
    __shared__ float inv_lds[RB];

    int tid = threadIdx.x;
    int gr0 = blockIdx.x * RB;            // global row base (= b*NS + s0)
    int b = gr0 >> 10;
    int w = tid >> 6, lane = tid & 63;

    // ---- Phase A: wave-redundant q features; lane l holds row l>>3, qubit l&7 ----
    unsigned vq0, vq1;
    {
        int r0 = lane >> 3, n0 = lane & 7;
        float t6[6];
        theta_table(theta_q, n0, t6);
        float s, c;
        tanh_sincos(x[(size_t)(gr0 + r0) * DK + n0], s, c);
        float d0, d1, ur, ui;
        qk_density(s, c, t6, d0, d1, ur, ui);
        __half2 h0 = __floats2half2_rn(d0, d1);
        __half2 h1 = __floats2half2_rn(ur, ui);
        vq0 = *(unsigned*)&h0;
        vq1 = *(unsigned*)&h1;
    }

    // ---- Phase 1: load wave's K slice (4 tokens per lane, 64 VGPRs) ----
    const __half* kfb = kdh + (size_t)b * NS * 32;
    int t0 = w * 256;
    uint4 kv[4][4];
#pragma unroll
    for (int j = 0; j < 4; ++j) {
        const uint4* kp = (const uint4*)(kfb + (size_t)(t0 + j * 64 + lane) * 32);
        kv[j][0] = kp[0]; kv[j][1] = kp[1]; kv[j][2] = kp[2]; kv[j][3] = kp[3];
    }

    float sums[RB];
#pragma unroll
    for (int r = 0; r < RB; ++r) sums[r] = 0.f;

#pragma unroll
    for (int r = 0; r < RB; ++r) {
        unsigned sq[16];
#pragma unroll
        for (int n = 0; n < 8; ++n) {
            sq[2 * n + 0] = __builtin_amdgcn_readlane(vq0, r * 8 + n);
            sq[2 * n + 1] = __builtin_amdgcn_readlane(vq1, r * 8 + n);
        }
#pragma unroll
        for (int j = 0; j < 4; ++j) {
            float m0 = fdot2h(sq[ 0], kv[j][0].x, fdot2h(sq[ 1], kv[j][0].y, 0.f));
            float m1 = fdot2h(sq[ 2], kv[j][0].z, fdot2h(sq[ 3], kv[j][0].w, 0.f));
            float m2 = fdot2h(sq[ 4], kv[j][1].x, fdot2h(sq[ 5], kv[j][1].y, 0.f));
            float m3 = fdot2h(sq[ 6], kv[j][1].z, fdot2h(sq[ 7], kv[j][1].w, 0.f));
            float m4 = fdot2h(sq[ 8], kv[j][2].x, fdot2h(sq[ 9], kv[j][2].y, 0.f));
            float m5 = fdot2h(sq[10], kv[j][2].z, fdot2h(sq[11], kv[j][2].w, 0.f));
            float m6 = fdot2h(sq[12], kv[j][3].x, fdot2h(sq[13], kv[j][3].y, 0.f));
            float m7 = fdot2h(sq[14], kv[j][3].z, fdot2h(sq[15], kv[j][3].w, 0.f));
            float core = ((m0 * m1) * (m2 * m3)) * ((m4 * m5) * (m6 * m7));
            float e = __expf(fmaf(core, 0.5f, 0.5f));   // score in [0.5,1] -> no max
            e16[r][t0 + j * 64 + lane] = __float2half_rn(e);
            sums[r] += e;
        }
    }

    // per-wave partial row sums -> cross-wave combine
#pragma unroll
    for (int r = 0; r < RB; ++r) {
#pragma unroll
        for (int m = 1; m < 64; m <<= 1) sums[r] += __shfl_xor(sums[r], m, 64);
    }
    if (lane == 0) {
#pragma unroll
        for (int r = 0; r < RB; ++r) red_lds[w][r] = sums[r];
    }
    __syncthreads();
    if (tid < RB)
        inv_lds[tid] = 1.f / (red_lds[0][tid] + red_lds[1][tid] + red_lds[2][tid] + red_lds[3][tid]);
    __syncthreads();

    // ---- Phase 2: write normalized attn (coalesced float4) ----
    float* ab = attn + (size_t)gr0 * NS;
#pragma unroll
    for (int r = 0; r < RB; ++r) {
        float iv = inv_lds[r];
        uint2 raw = *(const uint2*)&e16[r][tid * 4];
        __half2* hp = (__half2*)&raw;
        float2 lo = __half22float2(hp[0]), hi = __half22float2(hp[1]);
        *(float4*)&ab[(size_t)r * NS + tid * 4] =
            make_float4(lo.x * iv, lo.y * iv, hi.x * iv, hi.y * iv);
    }

    // ---- Phase 3: PV via dot2, consecutive-pair chunks (b128 e-reads) ----
    int tg = tid >> 4, dg = tid & 15;
    const __half* v2l = v2 + (size_t)b * 512 * 128 + dg * 8;
    float acc[RB][4];
#pragma unroll
    for (int r = 0; r < RB; ++r) { acc[r][0] = acc[r][1] = acc[r][2] = acc[r][3] = 0.f; }

    for (int jj = 0; jj < 8; ++jj) {
        int p0 = jj * 64 + tg * 4;
        uint4 vv0 = *(const uint4*)(v2l + (size_t)(p0 + 0) * 128);
        uint4 vv1 = *(const uint4*)(v2l + (size_t)(p0 + 1) * 128);
        uint4 vv2 = *(const uint4*)(v2l + (size_t)(p0 + 2) * 128);
        uint4 vv3 = *(const uint4*)(v2l + (size_t)(p0 + 3) * 128);
#pragma unroll
        for (int r = 0; r < RB; ++r) {
            uint4 ep = *(const uint4*)&e16[r][2 * p0];   // 4 pairs of e (16B, broadcast x16 lanes)
            acc[r][0] = fdot2h(ep.x, vv0.x, acc[r][0]);
            acc[r][1] = fdot2h(ep.x, vv0.y, acc[r][1]);
            acc[r][2] = fdot2h(ep.x, vv0.z, acc[r][2]);
            acc[r][3] = fdot2h(ep.x, vv0.w, acc[r][3]);
            acc[r][0] = fdot2h(ep.y, vv1.x, acc[r][0]);
            acc[r][1] = fdot2h(ep.y, vv1.y, acc[r][1]);
            acc[r][2] = fdot2h(ep.y, vv1.z, acc[r][2]);
            acc[r][3] = fdot2h(ep.y, vv1.w, acc[r][3]);
            acc[r][0] = fdot2h(ep.z, vv2.x, acc[r][0]);
            acc[r][1] = fdot2h(ep.z, vv2.y, acc[r][1]);
            acc[r][2] = fdot2h(ep.z, vv2.z, acc[r][2]);
            acc[r][3] = fdot2h(ep.z, vv2.w, acc[r][3]);
            acc[r][0] = fdot2h(ep.w, vv3.x, acc[r][0]);
            acc[r][1] = fdot2h(ep.w, vv3.y, acc[r][1]);
            acc[r][2] = fdot2h(ep.w, vv3.z, acc[r][2]);
            acc[r][3] = fdot2h(ep.w, vv3.w, acc[r][3]);
        }
    }

    // ---- out reduce: alias e16 as [16][4][64] fp32 scratch, two rounds ----
#pragma unroll
    for (int h = 0; h < 2; ++h) {
        __syncthreads();    // previous readers of e16/red done
#pragma unroll
        for (int r = 0; r < 4; ++r) {
            *(float4*)&red[((size_t)tg * 4 + r) * 64 + dg * 4] =
                make_float4(acc[h * 4 + r][0], acc[h * 4 + r][1],
                            acc[h * 4 + r][2], acc[h * 4 + r][3]);
        }
        __syncthreads();
        int r2 = tid >> 6, d = tid & 63;
        float o = 0.f;
#pragma unroll
        for (int g = 0; g < 16; ++g) o += red[((size_t)g * 4 + r2) * 64 + d];
        out[((size_t)(gr0 + h * 4 + r2)) * DK + d] = o * inv_lds[h * 4 + r2];
    }
}

extern "C" void kernel_launch(void* const* d_in, const int* in_sizes, int n_in,
                              void* d_out, int out_size, void* d_ws, size_t ws_size,
                              hipStream_t stream) {
    const float* x       = (const float*)d_in[0];
    const float* theta_q = (const float*)d_in[1];
    const float* theta_k = (const float*)d_in[2];
    const float* W_v     = (const float*)d_in[3];
    const float* b_v     = (const float*)d_in[4];

    float* out  = (float*)d_out;                        // [8,1024,64]
    float* attn = (float*)d_out + (size_t)NB * NS * DK; // [8,1024,1024]

    __half* kdh = (__half*)d_ws;                         // 512 KB fp16
    __half* v2  = kdh + (size_t)NB * NS * 32;            // 1 MB fp16 (pair-interleaved V)

    prep_kernel<<<1024 + NB * NS * NQ / 256, 256, 0, stream>>>(
        x, theta_k, W_v, b_v, kdh, v2);
    attn_kernel<<<NB * NS / RB, 256, 0, stream>>>(x, theta_q, kdh, v2, out, attn);
}